// Round 16
// baseline (32.831 us; speedup 1.0000x reference)
//
#include <hip/hip_runtime.h>
#include <hip/hip_bf16.h>
#include <math.h>

#define NT 64
#define NC 8
#define NK 1024

typedef __attribute__((ext_vector_type(8))) short bf16x8;
typedef __attribute__((ext_vector_type(4))) float f32x4;

__device__ __forceinline__ float2 cmul2(float2 a, float2 b) {
    return make_float2(fmaf(a.x, b.x, -a.y * b.y), fmaf(a.x, b.y, a.y * b.x));
}
// native trig; |x| <= ~101 rad -> err invisible under bf16 quantization
__device__ __forceinline__ void fast_sc(float x, float* s, float* c) {
    *s = __sinf(x); *c = __cosf(x);
}
__device__ __forceinline__ uint pack2(float x, float y) {
    __hip_bfloat162 h2 = __float22bfloat162_rn(make_float2(x, y));
    union { __hip_bfloat162 h; uint u; } cu; cu.h = h2; return cu.u;
}
// B1 frag (re,-im) -> B2 frag (im,re)  (verified R12/R13: absmax 0.25)
__device__ __forceinline__ bf16x8 b2_from(bf16x8 e) {
    union { bf16x8 v; uint u[4]; } in, out;
    in.v = e;
    #pragma unroll
    for (int i = 0; i < 4; ++i) {
        uint u = in.u[i];
        out.u[i] = ((u >> 16) | (u << 16)) ^ 0x8000u;
    }
    return out.v;
}

// ---------------------------------------------------------------------------
// prep: pack A = [img_re, img_im] in MFMA-frag-linear order (R9-verified map):
// uint4 slot t = (ac*16 + mt*4 + chunk)*64 + l holds (re,im) pairs for
// h = mt*16 + (l&15), w = chunk*16 + (l>>4)*4 + i. 512 KB.
// ---------------------------------------------------------------------------
__global__ __launch_bounds__(256) void prep_kernel(
    const float* __restrict__ xr, const float* __restrict__ xi,
    const float* __restrict__ mr, const float* __restrict__ mi,
    uint4* __restrict__ Ap)
{
    int t = blockIdx.x * 256 + threadIdx.x;   // 32768
    int l = t & 63;
    int chunk = (t >> 6) & 3;
    int mt = (t >> 8) & 3;
    int ac = t >> 10;
    int a = ac >> 3, c = ac & 7;
    int h = (mt << 4) + (l & 15);
    int w0 = (chunk << 4) + ((l >> 4) << 2);
    int off = (h << 6) + w0;
    float4 x4r = *(const float4*)(xr + (a << 12) + off);
    float4 x4i = *(const float4*)(xi + (a << 12) + off);
    float4 m4r = *(const float4*)(mr + (c << 12) + off);
    float4 m4i = *(const float4*)(mi + (c << 12) + off);
    uint4 pk;
    pk.x = pack2(x4r.x * m4r.x - x4i.x * m4i.x, x4r.x * m4i.x + x4i.x * m4r.x);
    pk.y = pack2(x4r.y * m4r.y - x4i.y * m4i.y, x4r.y * m4i.y + x4i.y * m4r.y);
    pk.z = pack2(x4r.z * m4r.z - x4i.z * m4i.z, x4r.z * m4i.z + x4i.z * m4r.z);
    pk.w = pack2(x4r.w * m4r.w - x4i.w * m4i.w, x4r.w * m4i.w + x4i.w * m4r.w);
    Ap[t] = pk;
}

// ---------------------------------------------------------------------------
// fused gemm+combine — BYTE-IDENTICAL to R14 (22.06us best). This round is a
// CALIBRATION: kernel_launch launches this twice (idempotent: each out element
// written by a unique thread with the same value) to measure the fused
// kernel's marginal cost, since the profiler floor hides our dispatches.
// ---------------------------------------------------------------------------
__global__ __launch_bounds__(256, 3) void fused_kernel(
    const uint4* __restrict__ Ap, const float* __restrict__ trj,
    const float* __restrict__ phi, const float* __restrict__ dcf,
    const int* __restrict__ sidx, float* __restrict__ out)
{
    __shared__ float Fs[8 * 33];     // [a*2+cc][kl]
    __shared__ float sphi[256];
    __shared__ int   ssidx[64];
    int b = blockIdx.x;              // 1024
    int rktile = b >> 2, cpair = b & 3;
    int tid = threadIdx.x;
    int wv = tid >> 6, l = tid & 63;
    int lg = l >> 4;
    int rkbase = rktile << 5;
    int r = rkbase >> 10;
    int acb = (wv << 3) + (cpair << 1);  // panel (a=wv, c=cpair*2), +1 = cc=1
    int wb = lg << 2;

    sphi[tid] = phi[tid];
    if (tid < 64) ssidx[tid] = sidx[tid];

    // issue first A-frag loads immediately (hide L2 latency under trig prologue)
    const uint4* ap0 = Ap + ((acb << 4) << 6) + l;
    uint4 c0 = ap0[0], c1 = ap0[64], c2 = ap0[128], c3 = ap0[192];

    int k0 = (rkbase + (l & 15)) & 1023;
    int k1 = (rkbase + 16 + (l & 15)) & 1023;
    float t0a = trj[(r << 11) + k0];
    float t0b = trj[(r << 11) + k1];
    float t1a = trj[(r << 11) + 1024 + k0];
    float t1b = trj[(r << 11) + 1024 + k1];

    // ---- B1-form frags only (B2 derived per use): B1=(Ewre,-Ewim)
    bf16x8 B1[2][4];
    #pragma unroll
    for (int s = 0; s < 2; ++s) {
        float t1 = s ? t1b : t1a;
        float sv, cv;
        float2 e, st1, st16;
        fast_sc(t1 * (float)(32 - wb), &sv, &cv); e = make_float2(cv, sv);
        fast_sc(-t1, &sv, &cv);         st1  = make_float2(cv, sv);
        fast_sc(-16.0f * t1, &sv, &cv); st16 = make_float2(cv, sv);
        #pragma unroll
        for (int ch = 0; ch < 4; ++ch) {
            float2 ec = e;
            union { uint u[4]; bf16x8 v; } f1;
            #pragma unroll
            for (int i = 0; i < 4; ++i) {
                f1.u[i] = pack2(ec.x, -ec.y);
                ec = cmul2(ec, st1);
            }
            B1[s][ch] = f1.v;
            e = cmul2(e, st16);
        }
    }

    // ---- Eh running state (advance by 16 rows per mt; 1 row inside q-chain)
    float sv, cv;
    float2 ehA, ehB, s1A, s1B, s16A, s16B;
    fast_sc(t0a * (float)(32 - wb), &sv, &cv); ehA = make_float2(cv, sv);
    fast_sc(-t0a, &sv, &cv);         s1A  = make_float2(cv, sv);
    fast_sc(-16.0f * t0a, &sv, &cv); s16A = make_float2(cv, sv);
    fast_sc(t0b * (float)(32 - wb), &sv, &cv); ehB = make_float2(cv, sv);
    fast_sc(-t0b, &sv, &cv);         s1B  = make_float2(cv, sv);
    fast_sc(-16.0f * t0b, &sv, &cv); s16B = make_float2(cv, sv);

    float ps00 = 0.f, ps01 = 0.f, ps10 = 0.f, ps11 = 0.f;  // [aci][sub]

    #pragma unroll
    for (int mt = 0; mt < 4; ++mt) {
        #pragma unroll
        for (int aci = 0; aci < 2; ++aci) {
            // ping-pong prefetch: issue next (mt,aci) loads BEFORE this iter's MFMAs
            int ni = (mt << 1) + aci + 1;
            uint4 n0, n1, n2, n3;
            if (ni < 8) {
                int nmt = ni >> 1, naci = ni & 1;
                const uint4* pn = Ap + ((((acb + naci) << 4) + (nmt << 2)) << 6) + l;
                n0 = pn[0]; n1 = pn[64]; n2 = pn[128]; n3 = pn[192];
            }
            f32x4 r0 = {0.f,0.f,0.f,0.f}, i0 = r0, r1 = r0, i1 = r0;
            union { uint4 u; bf16x8 v; } av;
            av.u = c0;
            r0 = __builtin_amdgcn_mfma_f32_16x16x32_bf16(av.v, B1[0][0], r0, 0,0,0);
            i0 = __builtin_amdgcn_mfma_f32_16x16x32_bf16(av.v, b2_from(B1[0][0]), i0, 0,0,0);
            r1 = __builtin_amdgcn_mfma_f32_16x16x32_bf16(av.v, B1[1][0], r1, 0,0,0);
            i1 = __builtin_amdgcn_mfma_f32_16x16x32_bf16(av.v, b2_from(B1[1][0]), i1, 0,0,0);
            av.u = c1;
            r0 = __builtin_amdgcn_mfma_f32_16x16x32_bf16(av.v, B1[0][1], r0, 0,0,0);
            i0 = __builtin_amdgcn_mfma_f32_16x16x32_bf16(av.v, b2_from(B1[0][1]), i0, 0,0,0);
            r1 = __builtin_amdgcn_mfma_f32_16x16x32_bf16(av.v, B1[1][1], r1, 0,0,0);
            i1 = __builtin_amdgcn_mfma_f32_16x16x32_bf16(av.v, b2_from(B1[1][1]), i1, 0,0,0);
            av.u = c2;
            r0 = __builtin_amdgcn_mfma_f32_16x16x32_bf16(av.v, B1[0][2], r0, 0,0,0);
            i0 = __builtin_amdgcn_mfma_f32_16x16x32_bf16(av.v, b2_from(B1[0][2]), i0, 0,0,0);
            r1 = __builtin_amdgcn_mfma_f32_16x16x32_bf16(av.v, B1[1][2], r1, 0,0,0);
            i1 = __builtin_amdgcn_mfma_f32_16x16x32_bf16(av.v, b2_from(B1[1][2]), i1, 0,0,0);
            av.u = c3;
            r0 = __builtin_amdgcn_mfma_f32_16x16x32_bf16(av.v, B1[0][3], r0, 0,0,0);
            i0 = __builtin_amdgcn_mfma_f32_16x16x32_bf16(av.v, b2_from(B1[0][3]), i0, 0,0,0);
            r1 = __builtin_amdgcn_mfma_f32_16x16x32_bf16(av.v, B1[1][3], r1, 0,0,0);
            i1 = __builtin_amdgcn_mfma_f32_16x16x32_bf16(av.v, b2_from(B1[1][3]), i1, 0,0,0);

            // stage-2: rows h = mt*16 + wb + q (verified C/D row map)
            float2 eA = ehA, eB = ehB;
            float pa = (aci == 0) ? ps00 : ps10;
            float pb = (aci == 0) ? ps01 : ps11;
            #pragma unroll
            for (int q = 0; q < 4; ++q) {
                pa = fmaf(eA.x, r0[q], fmaf(-eA.y, i0[q], pa));
                pb = fmaf(eB.x, r1[q], fmaf(-eB.y, i1[q], pb));
                eA = cmul2(eA, s1A);
                eB = cmul2(eB, s1B);
            }
            if (aci == 0) { ps00 = pa; ps01 = pb; }
            else          { ps10 = pa; ps11 = pb; }
            if (ni < 8) { c0 = n0; c1 = n1; c2 = n2; c3 = n3; }
        }
        ehA = cmul2(ehA, s16A);
        ehB = cmul2(ehB, s16B);
    }

    // sum the 4 row-groups per column
    ps00 += __shfl_xor(ps00, 16, 64); ps00 += __shfl_xor(ps00, 32, 64);
    ps01 += __shfl_xor(ps01, 16, 64); ps01 += __shfl_xor(ps01, 32, 64);
    ps10 += __shfl_xor(ps10, 16, 64); ps10 += __shfl_xor(ps10, 32, 64);
    ps11 += __shfl_xor(ps11, 16, 64); ps11 += __shfl_xor(ps11, 32, 64);

    if (l < 32) {
        int s = l >> 4;
        int kl = l & 31;
        float v0 = (s == 0) ? ps00 : ps01;   // panel aci=0 (cc=0)
        float v1 = (s == 0) ? ps10 : ps11;   // panel aci=1 (cc=1)
        Fs[(wv * 2 + 0) * 33 + kl] = v0;
        Fs[(wv * 2 + 1) * 33 + kl] = v1;
    }
    __syncthreads();

    // fused combine: out[t, cpair*2+cc, kgl] = dcf*scale * sum_a phi*Fs
    int kl = tid & 31, cc = (tid >> 5) & 1, tq = tid >> 6;
    int kgl = (rkbase & 1023) + kl;              // k within r
    int cglob = (cpair << 1) + cc;
    float dv = dcf[(r << 10) + kgl] * 0.03125f;  // scale = 2/sqrt(64*64)
    const float* Fsp = Fs + cc * 33 + kl;
    for (int t = tq; t < NT; t += 4) {
        if (ssidx[t] != r) continue;
        float s = 0.f;
        #pragma unroll
        for (int a = 0; a < 4; ++a)
            s = fmaf(sphi[a * 64 + t], Fsp[a * 66], s);   // 66 = 2*33
        out[(t << 13) + (cglob << 10) + kgl] = s * dv;
    }
}

// ---------------- fallback (proven round-3 path, no ws needed) --------------
__global__ __launch_bounds__(256) void ndft_atomic_kernel(
    const float* __restrict__ xr, const float* __restrict__ xi,
    const float* __restrict__ mr, const float* __restrict__ mi,
    const float* __restrict__ trj,
    const float* __restrict__ phi, const float* __restrict__ dcf,
    const int* __restrict__ sidx, float* __restrict__ out)
{
    __shared__ float2 simg[64 * 64];
    int b = blockIdx.x;
    int kq = b & 3, c = (b >> 2) & 7, a = (b >> 5) & 3, r = b >> 7;
    int tid = threadIdx.x;
    for (int i = tid; i < 64 * 64; i += 256) {
        float xre = xr[(a << 12) + i], xim = xi[(a << 12) + i];
        float mre = mr[(c << 12) + i], mim = mi[(c << 12) + i];
        simg[i] = make_float2(xre * mre - xim * mim, xre * mim + xim * mre);
    }
    __syncthreads();
    int k = (kq << 8) + tid;
    float t0 = trj[(r << 11) + k];
    float t1 = trj[(r << 11) + 1024 + k];
    float sv, cv;
    sincosf(-t1, &sv, &cv);        float2 ewb = make_float2(cv, sv);
    sincosf(32.0f * t1, &sv, &cv); float2 ews = make_float2(cv, sv);
    sincosf(-t0, &sv, &cv);        float2 ehb = make_float2(cv, sv);
    sincosf(32.0f * t0, &sv, &cv); float2 ehc = make_float2(cv, sv);
    float accx = 0.f;
    for (int h0 = 0; h0 < 64; h0 += 4) {
        float2 s0 = make_float2(0.f, 0.f), s1 = s0, s2 = s0, s3 = s0;
        const float2* i0 = simg + (h0 << 6);
        float2 ewc = ews;
        #pragma unroll 8
        for (int w = 0; w < 64; ++w) {
            float2 v0 = i0[w], v1 = i0[w+64], v2 = i0[w+128], v3 = i0[w+192];
            s0.x = fmaf(v0.x, ewc.x, fmaf(-v0.y, ewc.y, s0.x));
            s0.y = fmaf(v0.x, ewc.y, fmaf( v0.y, ewc.x, s0.y));
            s1.x = fmaf(v1.x, ewc.x, fmaf(-v1.y, ewc.y, s1.x));
            s1.y = fmaf(v1.x, ewc.y, fmaf( v1.y, ewc.x, s1.y));
            s2.x = fmaf(v2.x, ewc.x, fmaf(-v2.y, ewc.y, s2.x));
            s2.y = fmaf(v2.x, ewc.y, fmaf( v2.y, ewc.x, s2.y));
            s3.x = fmaf(v3.x, ewc.x, fmaf(-v3.y, ewc.y, s3.x));
            s3.y = fmaf(v3.x, ewc.y, fmaf( v3.y, ewc.x, s3.y));
            ewc = cmul2(ewc, ewb);
        }
        float2 e0 = ehc, e1 = cmul2(e0, ehb), e2 = cmul2(e1, ehb), e3 = cmul2(e2, ehb);
        ehc = cmul2(e3, ehb);
        accx = fmaf(s0.x, e0.x, fmaf(-s0.y, e0.y, accx));
        accx = fmaf(s1.x, e1.x, fmaf(-s1.y, e1.y, accx));
        accx = fmaf(s2.x, e2.x, fmaf(-s2.y, e2.y, accx));
        accx = fmaf(s3.x, e3.x, fmaf(-s3.y, e3.y, accx));
    }
    float d = dcf[(r << 10) + k] * 0.03125f;
    for (int t = 0; t < 64; ++t) {
        if (sidx[t] == r) atomicAdd(out + (t << 13) + (c << 10) + k, phi[a*64 + t] * d * accx);
    }
}

extern "C" void kernel_launch(void* const* d_in, const int* in_sizes, int n_in,
                              void* d_out, int out_size, void* d_ws, size_t ws_size,
                              hipStream_t stream)
{
    const float* x_re   = (const float*)d_in[0];
    const float* x_im   = (const float*)d_in[1];
    const float* mps_re = (const float*)d_in[2];
    const float* mps_im = (const float*)d_in[3];
    const float* phi    = (const float*)d_in[4];
    const float* dcf    = (const float*)d_in[5];
    const float* trj    = (const float*)d_in[6];
    const int*   sidx   = (const int*)d_in[7];
    float* out = (float*)d_out;

    const size_t A_bytes = 512 * 1024;   // packed A

    if (ws_size >= A_bytes) {
        uint4* Ap = (uint4*)d_ws;
        hipLaunchKernelGGL(prep_kernel, dim3(128), dim3(256), 0, stream,
                           x_re, x_im, mps_re, mps_im, Ap);
        // CALIBRATION: launch fused twice (idempotent — identical values
        // written by unique threads). dur_us - 22.06 ~= fused marginal cost.
        hipLaunchKernelGGL(fused_kernel, dim3(1024), dim3(256), 0, stream,
                           Ap, trj, phi, dcf, sidx, out);
        hipLaunchKernelGGL(fused_kernel, dim3(1024), dim3(256), 0, stream,
                           Ap, trj, phi, dcf, sidx, out);
    } else {
        hipMemsetAsync(d_out, 0, (size_t)out_size * sizeof(float), stream);
        hipLaunchKernelGGL(ndft_atomic_kernel, dim3(1024), dim3(256), 0, stream,
                           x_re, x_im, mps_re, mps_im, trj, phi, dcf, sidx, out);
    }
}

// Round 17
// 22.362 us; speedup vs baseline: 1.4681x; 1.4681x over previous
//
#include <hip/hip_runtime.h>
#include <hip/hip_bf16.h>
#include <math.h>

#define NT 64
#define NC 8
#define NK 1024

typedef __attribute__((ext_vector_type(8))) short bf16x8;
typedef __attribute__((ext_vector_type(4))) float f32x4;

__device__ __forceinline__ float2 cmul2(float2 a, float2 b) {
    return make_float2(fmaf(a.x, b.x, -a.y * b.y), fmaf(a.x, b.y, a.y * b.x));
}
// native trig; |x| <= ~101 rad -> err invisible under bf16 quantization
__device__ __forceinline__ void fast_sc(float x, float* s, float* c) {
    *s = __sinf(x); *c = __cosf(x);
}
__device__ __forceinline__ uint pack2(float x, float y) {
    __hip_bfloat162 h2 = __float22bfloat162_rn(make_float2(x, y));
    union { __hip_bfloat162 h; uint u; } cu; cu.h = h2; return cu.u;
}
// B1 frag (re,-im) -> B2 frag (im,re)  (verified R12/R13: absmax 0.25)
__device__ __forceinline__ bf16x8 b2_from(bf16x8 e) {
    union { bf16x8 v; uint u[4]; } in, out;
    in.v = e;
    #pragma unroll
    for (int i = 0; i < 4; ++i) {
        uint u = in.u[i];
        out.u[i] = ((u >> 16) | (u << 16)) ^ 0x8000u;
    }
    return out.v;
}

// ---------------------------------------------------------------------------
// prep: pack A = [img_re, img_im] in MFMA-frag-linear order (R9-verified map):
// uint4 slot t = (ac*16 + mt*4 + chunk)*64 + l holds (re,im) pairs for
// h = mt*16 + (l&15), w = chunk*16 + (l>>4)*4 + i. 512 KB.
// ---------------------------------------------------------------------------
__global__ __launch_bounds__(256) void prep_kernel(
    const float* __restrict__ xr, const float* __restrict__ xi,
    const float* __restrict__ mr, const float* __restrict__ mi,
    uint4* __restrict__ Ap)
{
    int t = blockIdx.x * 256 + threadIdx.x;   // 32768
    int l = t & 63;
    int chunk = (t >> 6) & 3;
    int mt = (t >> 8) & 3;
    int ac = t >> 10;
    int a = ac >> 3, c = ac & 7;
    int h = (mt << 4) + (l & 15);
    int w0 = (chunk << 4) + ((l >> 4) << 2);
    int off = (h << 6) + w0;
    float4 x4r = *(const float4*)(xr + (a << 12) + off);
    float4 x4i = *(const float4*)(xi + (a << 12) + off);
    float4 m4r = *(const float4*)(mr + (c << 12) + off);
    float4 m4i = *(const float4*)(mi + (c << 12) + off);
    uint4 pk;
    pk.x = pack2(x4r.x * m4r.x - x4i.x * m4i.x, x4r.x * m4i.x + x4i.x * m4r.x);
    pk.y = pack2(x4r.y * m4r.y - x4i.y * m4i.y, x4r.y * m4i.y + x4i.y * m4r.y);
    pk.z = pack2(x4r.z * m4r.z - x4i.z * m4i.z, x4r.z * m4i.z + x4i.z * m4r.z);
    pk.w = pack2(x4r.w * m4r.w - x4i.w * m4i.w, x4r.w * m4i.w + x4i.w * m4r.w);
    Ap[t] = pk;
}

// ---------------------------------------------------------------------------
// fused gemm+combine (R13 structure, B2 hoisted to prologue): 1024 blocks =
// 256 rk-tiles x 4 c-pairs; 256 threads; launch_bounds(256,3). Per-use
// b2_from (768 VALU inst/thread, ~48% of VALU issue) replaced by a one-time
// 96-inst prologue derivation (+32 VGPR). Maps identical to R9/R11/R13.
// ---------------------------------------------------------------------------
__global__ __launch_bounds__(256, 3) void fused_kernel(
    const uint4* __restrict__ Ap, const float* __restrict__ trj,
    const float* __restrict__ phi, const float* __restrict__ dcf,
    const int* __restrict__ sidx, float* __restrict__ out)
{
    __shared__ float Fs[8 * 33];     // [a*2+cc][kl]
    __shared__ float sphi[256];
    __shared__ int   ssidx[64];
    int b = blockIdx.x;              // 1024
    int rktile = b >> 2, cpair = b & 3;
    int tid = threadIdx.x;
    int wv = tid >> 6, l = tid & 63;
    int lg = l >> 4;
    int rkbase = rktile << 5;
    int r = rkbase >> 10;
    int acb = (wv << 3) + (cpair << 1);  // panel (a=wv, c=cpair*2), +1 = cc=1
    int wb = lg << 2;

    sphi[tid] = phi[tid];
    if (tid < 64) ssidx[tid] = sidx[tid];

    int k0 = (rkbase + (l & 15)) & 1023;
    int k1 = (rkbase + 16 + (l & 15)) & 1023;
    float t0a = trj[(r << 11) + k0];
    float t0b = trj[(r << 11) + k1];
    float t1a = trj[(r << 11) + 1024 + k0];
    float t1b = trj[(r << 11) + 1024 + k1];

    // ---- B frags: B1=(Ewre,-Ewim) generated, B2=(Ewim,Ewre) derived ONCE
    bf16x8 B1[2][4], B2[2][4];
    #pragma unroll
    for (int s = 0; s < 2; ++s) {
        float t1 = s ? t1b : t1a;
        float sv, cv;
        float2 e, st1, st16;
        fast_sc(t1 * (float)(32 - wb), &sv, &cv); e = make_float2(cv, sv);
        fast_sc(-t1, &sv, &cv);         st1  = make_float2(cv, sv);
        fast_sc(-16.0f * t1, &sv, &cv); st16 = make_float2(cv, sv);
        #pragma unroll
        for (int ch = 0; ch < 4; ++ch) {
            float2 ec = e;
            union { uint u[4]; bf16x8 v; } f1;
            #pragma unroll
            for (int i = 0; i < 4; ++i) {
                f1.u[i] = pack2(ec.x, -ec.y);
                ec = cmul2(ec, st1);
            }
            B1[s][ch] = f1.v;
            B2[s][ch] = b2_from(f1.v);
            e = cmul2(e, st16);
        }
    }

    // ---- Eh running state (advance by 16 rows per mt; 1 row inside q-chain)
    float sv, cv;
    float2 ehA, ehB, s1A, s1B, s16A, s16B;
    fast_sc(t0a * (float)(32 - wb), &sv, &cv); ehA = make_float2(cv, sv);
    fast_sc(-t0a, &sv, &cv);         s1A  = make_float2(cv, sv);
    fast_sc(-16.0f * t0a, &sv, &cv); s16A = make_float2(cv, sv);
    fast_sc(t0b * (float)(32 - wb), &sv, &cv); ehB = make_float2(cv, sv);
    fast_sc(-t0b, &sv, &cv);         s1B  = make_float2(cv, sv);
    fast_sc(-16.0f * t0b, &sv, &cv); s16B = make_float2(cv, sv);

    float ps00 = 0.f, ps01 = 0.f, ps10 = 0.f, ps11 = 0.f;  // [aci][sub]

    #pragma unroll
    for (int mt = 0; mt < 4; ++mt) {
        #pragma unroll
        for (int aci = 0; aci < 2; ++aci) {
            int ac = acb + aci;
            const uint4* ap = Ap + (((ac << 4) + (mt << 2)) << 6) + l;
            uint4 a0 = ap[0];
            uint4 a1 = ap[64];
            uint4 a2 = ap[128];
            uint4 a3 = ap[192];
            f32x4 r0 = {0.f,0.f,0.f,0.f}, i0 = r0, r1 = r0, i1 = r0;
            union { uint4 u; bf16x8 v; } av;
            av.u = a0;
            r0 = __builtin_amdgcn_mfma_f32_16x16x32_bf16(av.v, B1[0][0], r0, 0,0,0);
            i0 = __builtin_amdgcn_mfma_f32_16x16x32_bf16(av.v, B2[0][0], i0, 0,0,0);
            r1 = __builtin_amdgcn_mfma_f32_16x16x32_bf16(av.v, B1[1][0], r1, 0,0,0);
            i1 = __builtin_amdgcn_mfma_f32_16x16x32_bf16(av.v, B2[1][0], i1, 0,0,0);
            av.u = a1;
            r0 = __builtin_amdgcn_mfma_f32_16x16x32_bf16(av.v, B1[0][1], r0, 0,0,0);
            i0 = __builtin_amdgcn_mfma_f32_16x16x32_bf16(av.v, B2[0][1], i0, 0,0,0);
            r1 = __builtin_amdgcn_mfma_f32_16x16x32_bf16(av.v, B1[1][1], r1, 0,0,0);
            i1 = __builtin_amdgcn_mfma_f32_16x16x32_bf16(av.v, B2[1][1], i1, 0,0,0);
            av.u = a2;
            r0 = __builtin_amdgcn_mfma_f32_16x16x32_bf16(av.v, B1[0][2], r0, 0,0,0);
            i0 = __builtin_amdgcn_mfma_f32_16x16x32_bf16(av.v, B2[0][2], i0, 0,0,0);
            r1 = __builtin_amdgcn_mfma_f32_16x16x32_bf16(av.v, B1[1][2], r1, 0,0,0);
            i1 = __builtin_amdgcn_mfma_f32_16x16x32_bf16(av.v, B2[1][2], i1, 0,0,0);
            av.u = a3;
            r0 = __builtin_amdgcn_mfma_f32_16x16x32_bf16(av.v, B1[0][3], r0, 0,0,0);
            i0 = __builtin_amdgcn_mfma_f32_16x16x32_bf16(av.v, B2[0][3], i0, 0,0,0);
            r1 = __builtin_amdgcn_mfma_f32_16x16x32_bf16(av.v, B1[1][3], r1, 0,0,0);
            i1 = __builtin_amdgcn_mfma_f32_16x16x32_bf16(av.v, B2[1][3], i1, 0,0,0);

            // stage-2: rows h = mt*16 + wb + q (verified C/D row map)
            float2 eA = ehA, eB = ehB;
            float pa = (aci == 0) ? ps00 : ps10;
            float pb = (aci == 0) ? ps01 : ps11;
            #pragma unroll
            for (int q = 0; q < 4; ++q) {
                pa = fmaf(eA.x, r0[q], fmaf(-eA.y, i0[q], pa));
                pb = fmaf(eB.x, r1[q], fmaf(-eB.y, i1[q], pb));
                eA = cmul2(eA, s1A);
                eB = cmul2(eB, s1B);
            }
            if (aci == 0) { ps00 = pa; ps01 = pb; }
            else          { ps10 = pa; ps11 = pb; }
        }
        ehA = cmul2(ehA, s16A);
        ehB = cmul2(ehB, s16B);
    }

    // sum the 4 row-groups per column
    ps00 += __shfl_xor(ps00, 16, 64); ps00 += __shfl_xor(ps00, 32, 64);
    ps01 += __shfl_xor(ps01, 16, 64); ps01 += __shfl_xor(ps01, 32, 64);
    ps10 += __shfl_xor(ps10, 16, 64); ps10 += __shfl_xor(ps10, 32, 64);
    ps11 += __shfl_xor(ps11, 16, 64); ps11 += __shfl_xor(ps11, 32, 64);

    if (l < 32) {
        int s = l >> 4;
        int kl = l & 31;
        float v0 = (s == 0) ? ps00 : ps01;   // panel aci=0 (cc=0)
        float v1 = (s == 0) ? ps10 : ps11;   // panel aci=1 (cc=1)
        Fs[(wv * 2 + 0) * 33 + kl] = v0;
        Fs[(wv * 2 + 1) * 33 + kl] = v1;
    }
    __syncthreads();

    // fused combine: out[t, cpair*2+cc, kgl] = dcf*scale * sum_a phi*Fs
    int kl = tid & 31, cc = (tid >> 5) & 1, tq = tid >> 6;
    int kgl = (rkbase & 1023) + kl;              // k within r
    int cglob = (cpair << 1) + cc;
    float dv = dcf[(r << 10) + kgl] * 0.03125f;  // scale = 2/sqrt(64*64)
    const float* Fsp = Fs + cc * 33 + kl;
    for (int t = tq; t < NT; t += 4) {
        if (ssidx[t] != r) continue;
        float s = 0.f;
        #pragma unroll
        for (int a = 0; a < 4; ++a)
            s = fmaf(sphi[a * 64 + t], Fsp[a * 66], s);   // 66 = 2*33
        out[(t << 13) + (cglob << 10) + kgl] = s * dv;
    }
}

// ---------------- fallback (proven round-3 path, no ws needed) --------------
__global__ __launch_bounds__(256) void ndft_atomic_kernel(
    const float* __restrict__ xr, const float* __restrict__ xi,
    const float* __restrict__ mr, const float* __restrict__ mi,
    const float* __restrict__ trj,
    const float* __restrict__ phi, const float* __restrict__ dcf,
    const int* __restrict__ sidx, float* __restrict__ out)
{
    __shared__ float2 simg[64 * 64];
    int b = blockIdx.x;
    int kq = b & 3, c = (b >> 2) & 7, a = (b >> 5) & 3, r = b >> 7;
    int tid = threadIdx.x;
    for (int i = tid; i < 64 * 64; i += 256) {
        float xre = xr[(a << 12) + i], xim = xi[(a << 12) + i];
        float mre = mr[(c << 12) + i], mim = mi[(c << 12) + i];
        simg[i] = make_float2(xre * mre - xim * mim, xre * mim + xim * mre);
    }
    __syncthreads();
    int k = (kq << 8) + tid;
    float t0 = trj[(r << 11) + k];
    float t1 = trj[(r << 11) + 1024 + k];
    float sv, cv;
    sincosf(-t1, &sv, &cv);        float2 ewb = make_float2(cv, sv);
    sincosf(32.0f * t1, &sv, &cv); float2 ews = make_float2(cv, sv);
    sincosf(-t0, &sv, &cv);        float2 ehb = make_float2(cv, sv);
    sincosf(32.0f * t0, &sv, &cv); float2 ehc = make_float2(cv, sv);
    float accx = 0.f;
    for (int h0 = 0; h0 < 64; h0 += 4) {
        float2 s0 = make_float2(0.f, 0.f), s1 = s0, s2 = s0, s3 = s0;
        const float2* i0 = simg + (h0 << 6);
        float2 ewc = ews;
        #pragma unroll 8
        for (int w = 0; w < 64; ++w) {
            float2 v0 = i0[w], v1 = i0[w+64], v2 = i0[w+128], v3 = i0[w+192];
            s0.x = fmaf(v0.x, ewc.x, fmaf(-v0.y, ewc.y, s0.x));
            s0.y = fmaf(v0.x, ewc.y, fmaf( v0.y, ewc.x, s0.y));
            s1.x = fmaf(v1.x, ewc.x, fmaf(-v1.y, ewc.y, s1.x));
            s1.y = fmaf(v1.x, ewc.y, fmaf( v1.y, ewc.x, s1.y));
            s2.x = fmaf(v2.x, ewc.x, fmaf(-v2.y, ewc.y, s2.x));
            s2.y = fmaf(v2.x, ewc.y, fmaf( v2.y, ewc.x, s2.y));
            s3.x = fmaf(v3.x, ewc.x, fmaf(-v3.y, ewc.y, s3.x));
            s3.y = fmaf(v3.x, ewc.y, fmaf( v3.y, ewc.x, s3.y));
            ewc = cmul2(ewc, ewb);
        }
        float2 e0 = ehc, e1 = cmul2(e0, ehb), e2 = cmul2(e1, ehb), e3 = cmul2(e2, ehb);
        ehc = cmul2(e3, ehb);
        accx = fmaf(s0.x, e0.x, fmaf(-s0.y, e0.y, accx));
        accx = fmaf(s1.x, e1.x, fmaf(-s1.y, e1.y, accx));
        accx = fmaf(s2.x, e2.x, fmaf(-s2.y, e2.y, accx));
        accx = fmaf(s3.x, e3.x, fmaf(-s3.y, e3.y, accx));
    }
    float d = dcf[(r << 10) + k] * 0.03125f;
    for (int t = 0; t < 64; ++t) {
        if (sidx[t] == r) atomicAdd(out + (t << 13) + (c << 10) + k, phi[a*64 + t] * d * accx);
    }
}

extern "C" void kernel_launch(void* const* d_in, const int* in_sizes, int n_in,
                              void* d_out, int out_size, void* d_ws, size_t ws_size,
                              hipStream_t stream)
{
    const float* x_re   = (const float*)d_in[0];
    const float* x_im   = (const float*)d_in[1];
    const float* mps_re = (const float*)d_in[2];
    const float* mps_im = (const float*)d_in[3];
    const float* phi    = (const float*)d_in[4];
    const float* dcf    = (const float*)d_in[5];
    const float* trj    = (const float*)d_in[6];
    const int*   sidx   = (const int*)d_in[7];
    float* out = (float*)d_out;

    const size_t A_bytes = 512 * 1024;   // packed A

    if (ws_size >= A_bytes) {
        uint4* Ap = (uint4*)d_ws;
        hipLaunchKernelGGL(prep_kernel, dim3(128), dim3(256), 0, stream,
                           x_re, x_im, mps_re, mps_im, Ap);
        hipLaunchKernelGGL(fused_kernel, dim3(1024), dim3(256), 0, stream,
                           Ap, trj, phi, dcf, sidx, out);
    } else {
        hipMemsetAsync(d_out, 0, (size_t)out_size * sizeof(float), stream);
        hipLaunchKernelGGL(ndft_atomic_kernel, dim3(1024), dim3(256), 0, stream,
                           x_re, x_im, mps_re, mps_im, trj, phi, dcf, sidx, out);
    }
}

// Round 18
// 22.057 us; speedup vs baseline: 1.4885x; 1.0139x over previous
//
#include <hip/hip_runtime.h>
#include <hip/hip_bf16.h>
#include <math.h>

#define NT 64
#define NC 8
#define NK 1024

typedef __attribute__((ext_vector_type(8))) short bf16x8;
typedef __attribute__((ext_vector_type(4))) float f32x4;

__device__ __forceinline__ float2 cmul2(float2 a, float2 b) {
    return make_float2(fmaf(a.x, b.x, -a.y * b.y), fmaf(a.x, b.y, a.y * b.x));
}
// native trig; |x| <= ~101 rad -> err invisible under bf16 quantization
__device__ __forceinline__ void fast_sc(float x, float* s, float* c) {
    *s = __sinf(x); *c = __cosf(x);
}
__device__ __forceinline__ uint pack2(float x, float y) {
    __hip_bfloat162 h2 = __float22bfloat162_rn(make_float2(x, y));
    union { __hip_bfloat162 h; uint u; } cu; cu.h = h2; return cu.u;
}
// B1 frag (re,-im) -> B2 frag (im,re)  (verified R12/R13: absmax 0.25)
__device__ __forceinline__ bf16x8 b2_from(bf16x8 e) {
    union { bf16x8 v; uint u[4]; } in, out;
    in.v = e;
    #pragma unroll
    for (int i = 0; i < 4; ++i) {
        uint u = in.u[i];
        out.u[i] = ((u >> 16) | (u << 16)) ^ 0x8000u;
    }
    return out.v;
}

// ---------------------------------------------------------------------------
// prep: pack A = [img_re, img_im] in MFMA-frag-linear order (R9-verified map):
// uint4 slot t = (ac*16 + mt*4 + chunk)*64 + l holds (re,im) pairs for
// h = mt*16 + (l&15), w = chunk*16 + (l>>4)*4 + i. 512 KB.
// ---------------------------------------------------------------------------
__global__ __launch_bounds__(256) void prep_kernel(
    const float* __restrict__ xr, const float* __restrict__ xi,
    const float* __restrict__ mr, const float* __restrict__ mi,
    uint4* __restrict__ Ap)
{
    int t = blockIdx.x * 256 + threadIdx.x;   // 32768
    int l = t & 63;
    int chunk = (t >> 6) & 3;
    int mt = (t >> 8) & 3;
    int ac = t >> 10;
    int a = ac >> 3, c = ac & 7;
    int h = (mt << 4) + (l & 15);
    int w0 = (chunk << 4) + ((l >> 4) << 2);
    int off = (h << 6) + w0;
    float4 x4r = *(const float4*)(xr + (a << 12) + off);
    float4 x4i = *(const float4*)(xi + (a << 12) + off);
    float4 m4r = *(const float4*)(mr + (c << 12) + off);
    float4 m4i = *(const float4*)(mi + (c << 12) + off);
    uint4 pk;
    pk.x = pack2(x4r.x * m4r.x - x4i.x * m4i.x, x4r.x * m4i.x + x4i.x * m4r.x);
    pk.y = pack2(x4r.y * m4r.y - x4i.y * m4i.y, x4r.y * m4i.y + x4i.y * m4r.y);
    pk.z = pack2(x4r.z * m4r.z - x4i.z * m4i.z, x4r.z * m4i.z + x4i.z * m4r.z);
    pk.w = pack2(x4r.w * m4r.w - x4i.w * m4i.w, x4r.w * m4i.w + x4i.w * m4r.w);
    Ap[t] = pk;
}

// ---------------------------------------------------------------------------
// fused gemm+combine — exact R14 kernel (best measured: 22.06 us).
// 1024 blocks = 256 rk-tiles x 4 c-pairs; 256 threads; launch_bounds(256,3);
// ping-pong A-frag prefetch; B2 derived per use; fused phi/dcf epilogue.
// ---------------------------------------------------------------------------
__global__ __launch_bounds__(256, 3) void fused_kernel(
    const uint4* __restrict__ Ap, const float* __restrict__ trj,
    const float* __restrict__ phi, const float* __restrict__ dcf,
    const int* __restrict__ sidx, float* __restrict__ out)
{
    __shared__ float Fs[8 * 33];     // [a*2+cc][kl]
    __shared__ float sphi[256];
    __shared__ int   ssidx[64];
    int b = blockIdx.x;              // 1024
    int rktile = b >> 2, cpair = b & 3;
    int tid = threadIdx.x;
    int wv = tid >> 6, l = tid & 63;
    int lg = l >> 4;
    int rkbase = rktile << 5;
    int r = rkbase >> 10;
    int acb = (wv << 3) + (cpair << 1);  // panel (a=wv, c=cpair*2), +1 = cc=1
    int wb = lg << 2;

    sphi[tid] = phi[tid];
    if (tid < 64) ssidx[tid] = sidx[tid];

    // issue first A-frag loads immediately (hide L2 latency under trig prologue)
    const uint4* ap0 = Ap + ((acb << 4) << 6) + l;
    uint4 c0 = ap0[0], c1 = ap0[64], c2 = ap0[128], c3 = ap0[192];

    int k0 = (rkbase + (l & 15)) & 1023;
    int k1 = (rkbase + 16 + (l & 15)) & 1023;
    float t0a = trj[(r << 11) + k0];
    float t0b = trj[(r << 11) + k1];
    float t1a = trj[(r << 11) + 1024 + k0];
    float t1b = trj[(r << 11) + 1024 + k1];

    // ---- B1-form frags only (B2 derived per use): B1=(Ewre,-Ewim)
    bf16x8 B1[2][4];
    #pragma unroll
    for (int s = 0; s < 2; ++s) {
        float t1 = s ? t1b : t1a;
        float sv, cv;
        float2 e, st1, st16;
        fast_sc(t1 * (float)(32 - wb), &sv, &cv); e = make_float2(cv, sv);
        fast_sc(-t1, &sv, &cv);         st1  = make_float2(cv, sv);
        fast_sc(-16.0f * t1, &sv, &cv); st16 = make_float2(cv, sv);
        #pragma unroll
        for (int ch = 0; ch < 4; ++ch) {
            float2 ec = e;
            union { uint u[4]; bf16x8 v; } f1;
            #pragma unroll
            for (int i = 0; i < 4; ++i) {
                f1.u[i] = pack2(ec.x, -ec.y);
                ec = cmul2(ec, st1);
            }
            B1[s][ch] = f1.v;
            e = cmul2(e, st16);
        }
    }

    // ---- Eh running state (advance by 16 rows per mt; 1 row inside q-chain)
    float sv, cv;
    float2 ehA, ehB, s1A, s1B, s16A, s16B;
    fast_sc(t0a * (float)(32 - wb), &sv, &cv); ehA = make_float2(cv, sv);
    fast_sc(-t0a, &sv, &cv);         s1A  = make_float2(cv, sv);
    fast_sc(-16.0f * t0a, &sv, &cv); s16A = make_float2(cv, sv);
    fast_sc(t0b * (float)(32 - wb), &sv, &cv); ehB = make_float2(cv, sv);
    fast_sc(-t0b, &sv, &cv);         s1B  = make_float2(cv, sv);
    fast_sc(-16.0f * t0b, &sv, &cv); s16B = make_float2(cv, sv);

    float ps00 = 0.f, ps01 = 0.f, ps10 = 0.f, ps11 = 0.f;  // [aci][sub]

    #pragma unroll
    for (int mt = 0; mt < 4; ++mt) {
        #pragma unroll
        for (int aci = 0; aci < 2; ++aci) {
            // ping-pong prefetch: issue next (mt,aci) loads BEFORE this iter's MFMAs
            int ni = (mt << 1) + aci + 1;
            uint4 n0, n1, n2, n3;
            if (ni < 8) {
                int nmt = ni >> 1, naci = ni & 1;
                const uint4* pn = Ap + ((((acb + naci) << 4) + (nmt << 2)) << 6) + l;
                n0 = pn[0]; n1 = pn[64]; n2 = pn[128]; n3 = pn[192];
            }
            f32x4 r0 = {0.f,0.f,0.f,0.f}, i0 = r0, r1 = r0, i1 = r0;
            union { uint4 u; bf16x8 v; } av;
            av.u = c0;
            r0 = __builtin_amdgcn_mfma_f32_16x16x32_bf16(av.v, B1[0][0], r0, 0,0,0);
            i0 = __builtin_amdgcn_mfma_f32_16x16x32_bf16(av.v, b2_from(B1[0][0]), i0, 0,0,0);
            r1 = __builtin_amdgcn_mfma_f32_16x16x32_bf16(av.v, B1[1][0], r1, 0,0,0);
            i1 = __builtin_amdgcn_mfma_f32_16x16x32_bf16(av.v, b2_from(B1[1][0]), i1, 0,0,0);
            av.u = c1;
            r0 = __builtin_amdgcn_mfma_f32_16x16x32_bf16(av.v, B1[0][1], r0, 0,0,0);
            i0 = __builtin_amdgcn_mfma_f32_16x16x32_bf16(av.v, b2_from(B1[0][1]), i0, 0,0,0);
            r1 = __builtin_amdgcn_mfma_f32_16x16x32_bf16(av.v, B1[1][1], r1, 0,0,0);
            i1 = __builtin_amdgcn_mfma_f32_16x16x32_bf16(av.v, b2_from(B1[1][1]), i1, 0,0,0);
            av.u = c2;
            r0 = __builtin_amdgcn_mfma_f32_16x16x32_bf16(av.v, B1[0][2], r0, 0,0,0);
            i0 = __builtin_amdgcn_mfma_f32_16x16x32_bf16(av.v, b2_from(B1[0][2]), i0, 0,0,0);
            r1 = __builtin_amdgcn_mfma_f32_16x16x32_bf16(av.v, B1[1][2], r1, 0,0,0);
            i1 = __builtin_amdgcn_mfma_f32_16x16x32_bf16(av.v, b2_from(B1[1][2]), i1, 0,0,0);
            av.u = c3;
            r0 = __builtin_amdgcn_mfma_f32_16x16x32_bf16(av.v, B1[0][3], r0, 0,0,0);
            i0 = __builtin_amdgcn_mfma_f32_16x16x32_bf16(av.v, b2_from(B1[0][3]), i0, 0,0,0);
            r1 = __builtin_amdgcn_mfma_f32_16x16x32_bf16(av.v, B1[1][3], r1, 0,0,0);
            i1 = __builtin_amdgcn_mfma_f32_16x16x32_bf16(av.v, b2_from(B1[1][3]), i1, 0,0,0);

            // stage-2: rows h = mt*16 + wb + q (verified C/D row map)
            float2 eA = ehA, eB = ehB;
            float pa = (aci == 0) ? ps00 : ps10;
            float pb = (aci == 0) ? ps01 : ps11;
            #pragma unroll
            for (int q = 0; q < 4; ++q) {
                pa = fmaf(eA.x, r0[q], fmaf(-eA.y, i0[q], pa));
                pb = fmaf(eB.x, r1[q], fmaf(-eB.y, i1[q], pb));
                eA = cmul2(eA, s1A);
                eB = cmul2(eB, s1B);
            }
            if (aci == 0) { ps00 = pa; ps01 = pb; }
            else          { ps10 = pa; ps11 = pb; }
            if (ni < 8) { c0 = n0; c1 = n1; c2 = n2; c3 = n3; }
        }
        ehA = cmul2(ehA, s16A);
        ehB = cmul2(ehB, s16B);
    }

    // sum the 4 row-groups per column
    ps00 += __shfl_xor(ps00, 16, 64); ps00 += __shfl_xor(ps00, 32, 64);
    ps01 += __shfl_xor(ps01, 16, 64); ps01 += __shfl_xor(ps01, 32, 64);
    ps10 += __shfl_xor(ps10, 16, 64); ps10 += __shfl_xor(ps10, 32, 64);
    ps11 += __shfl_xor(ps11, 16, 64); ps11 += __shfl_xor(ps11, 32, 64);

    if (l < 32) {
        int s = l >> 4;
        int kl = l & 31;
        float v0 = (s == 0) ? ps00 : ps01;   // panel aci=0 (cc=0)
        float v1 = (s == 0) ? ps10 : ps11;   // panel aci=1 (cc=1)
        Fs[(wv * 2 + 0) * 33 + kl] = v0;
        Fs[(wv * 2 + 1) * 33 + kl] = v1;
    }
    __syncthreads();

    // fused combine: out[t, cpair*2+cc, kgl] = dcf*scale * sum_a phi*Fs
    int kl = tid & 31, cc = (tid >> 5) & 1, tq = tid >> 6;
    int kgl = (rkbase & 1023) + kl;              // k within r
    int cglob = (cpair << 1) + cc;
    float dv = dcf[(r << 10) + kgl] * 0.03125f;  // scale = 2/sqrt(64*64)
    const float* Fsp = Fs + cc * 33 + kl;
    for (int t = tq; t < NT; t += 4) {
        if (ssidx[t] != r) continue;
        float s = 0.f;
        #pragma unroll
        for (int a = 0; a < 4; ++a)
            s = fmaf(sphi[a * 64 + t], Fsp[a * 66], s);   // 66 = 2*33
        out[(t << 13) + (cglob << 10) + kgl] = s * dv;
    }
}

// ---------------- fallback (proven round-3 path, no ws needed) --------------
__global__ __launch_bounds__(256) void ndft_atomic_kernel(
    const float* __restrict__ xr, const float* __restrict__ xi,
    const float* __restrict__ mr, const float* __restrict__ mi,
    const float* __restrict__ trj,
    const float* __restrict__ phi, const float* __restrict__ dcf,
    const int* __restrict__ sidx, float* __restrict__ out)
{
    __shared__ float2 simg[64 * 64];
    int b = blockIdx.x;
    int kq = b & 3, c = (b >> 2) & 7, a = (b >> 5) & 3, r = b >> 7;
    int tid = threadIdx.x;
    for (int i = tid; i < 64 * 64; i += 256) {
        float xre = xr[(a << 12) + i], xim = xi[(a << 12) + i];
        float mre = mr[(c << 12) + i], mim = mi[(c << 12) + i];
        simg[i] = make_float2(xre * mre - xim * mim, xre * mim + xim * mre);
    }
    __syncthreads();
    int k = (kq << 8) + tid;
    float t0 = trj[(r << 11) + k];
    float t1 = trj[(r << 11) + 1024 + k];
    float sv, cv;
    sincosf(-t1, &sv, &cv);        float2 ewb = make_float2(cv, sv);
    sincosf(32.0f * t1, &sv, &cv); float2 ews = make_float2(cv, sv);
    sincosf(-t0, &sv, &cv);        float2 ehb = make_float2(cv, sv);
    sincosf(32.0f * t0, &sv, &cv); float2 ehc = make_float2(cv, sv);
    float accx = 0.f;
    for (int h0 = 0; h0 < 64; h0 += 4) {
        float2 s0 = make_float2(0.f, 0.f), s1 = s0, s2 = s0, s3 = s0;
        const float2* i0 = simg + (h0 << 6);
        float2 ewc = ews;
        #pragma unroll 8
        for (int w = 0; w < 64; ++w) {
            float2 v0 = i0[w], v1 = i0[w+64], v2 = i0[w+128], v3 = i0[w+192];
            s0.x = fmaf(v0.x, ewc.x, fmaf(-v0.y, ewc.y, s0.x));
            s0.y = fmaf(v0.x, ewc.y, fmaf( v0.y, ewc.x, s0.y));
            s1.x = fmaf(v1.x, ewc.x, fmaf(-v1.y, ewc.y, s1.x));
            s1.y = fmaf(v1.x, ewc.y, fmaf( v1.y, ewc.x, s1.y));
            s2.x = fmaf(v2.x, ewc.x, fmaf(-v2.y, ewc.y, s2.x));
            s2.y = fmaf(v2.x, ewc.y, fmaf( v2.y, ewc.x, s2.y));
            s3.x = fmaf(v3.x, ewc.x, fmaf(-v3.y, ewc.y, s3.x));
            s3.y = fmaf(v3.x, ewc.y, fmaf( v3.y, ewc.x, s3.y));
            ewc = cmul2(ewc, ewb);
        }
        float2 e0 = ehc, e1 = cmul2(e0, ehb), e2 = cmul2(e1, ehb), e3 = cmul2(e2, ehb);
        ehc = cmul2(e3, ehb);
        accx = fmaf(s0.x, e0.x, fmaf(-s0.y, e0.y, accx));
        accx = fmaf(s1.x, e1.x, fmaf(-s1.y, e1.y, accx));
        accx = fmaf(s2.x, e2.x, fmaf(-s2.y, e2.y, accx));
        accx = fmaf(s3.x, e3.x, fmaf(-s3.y, e3.y, accx));
    }
    float d = dcf[(r << 10) + k] * 0.03125f;
    for (int t = 0; t < 64; ++t) {
        if (sidx[t] == r) atomicAdd(out + (t << 13) + (c << 10) + k, phi[a*64 + t] * d * accx);
    }
}

extern "C" void kernel_launch(void* const* d_in, const int* in_sizes, int n_in,
                              void* d_out, int out_size, void* d_ws, size_t ws_size,
                              hipStream_t stream)
{
    const float* x_re   = (const float*)d_in[0];
    const float* x_im   = (const float*)d_in[1];
    const float* mps_re = (const float*)d_in[2];
    const float* mps_im = (const float*)d_in[3];
    const float* phi    = (const float*)d_in[4];
    const float* dcf    = (const float*)d_in[5];
    const float* trj    = (const float*)d_in[6];
    const int*   sidx   = (const int*)d_in[7];
    float* out = (float*)d_out;

    const size_t A_bytes = 512 * 1024;   // packed A

    if (ws_size >= A_bytes) {
        uint4* Ap = (uint4*)d_ws;
        hipLaunchKernelGGL(prep_kernel, dim3(128), dim3(256), 0, stream,
                           x_re, x_im, mps_re, mps_im, Ap);
        hipLaunchKernelGGL(fused_kernel, dim3(1024), dim3(256), 0, stream,
                           Ap, trj, phi, dcf, sidx, out);
    } else {
        hipMemsetAsync(d_out, 0, (size_t)out_size * sizeof(float), stream);
        hipLaunchKernelGGL(ndft_atomic_kernel, dim3(1024), dim3(256), 0, stream,
                           x_re, x_im, mps_re, mps_im, trj, phi, dcf, sidx, out);
    }
}